// Round 2
// baseline (4122.405 us; speedup 1.0000x reference)
//
#include <hip/hip_runtime.h>

#define N_ 128
#define T_ 128
#define V_ 25
#define TV 3200
#define LL 3
#define SS 5
#define II 16
#define EPSB 1e-5f
#define MCNT 409600.0f

// stats float2 slots: c1:[0,48) c2:[48,288) new:[288,352) y:[352,416) t:[416,448) p:[448,464)

__device__ __forceinline__ float2 bncoef(const float2* st, int slot, float g, float bt){
  float2 s = st[slot];
  float m  = s.x * (1.0f/MCNT);
  float var = s.y * (1.0f/MCNT) - m*m;
  float a = g * rsqrtf(var + EPSB);
  return make_float2(a, bt - m*a);
}

// ---------------- K1: c1[l] = x * gdw[l]^T + gdb[l]  (48 out channels), + stats ----------------
__global__ __launch_bounds__(256) void k1_conv_dw(
    const float* __restrict__ x, const float* __restrict__ gdw, const float* __restrict__ gdb,
    float* __restrict__ c1, float2* st)
{
  __shared__ float w[64*48];      // w[c*48+o] = gdw[o*64+c]
  __shared__ float bias[48];
  __shared__ float bst[4][96];
  const int tid = threadIdx.x;
  for (int i = tid; i < 64*48; i += 256){ int c = i/48, o = i - c*48; w[i] = gdw[o*64 + c]; }
  if (tid < 48) bias[tid] = gdb[tid];
  __syncthreads();
  const int n = blockIdx.y;
  const int rem = blockIdx.x*256 + tid;
  const bool act = rem < TV;
  float acc[48];
  #pragma unroll
  for (int o = 0; o < 48; o++) acc[o] = act ? bias[o] : 0.f;
  const float* xp = x + (size_t)n*64*TV + rem;
  if (act){
    #pragma unroll 4
    for (int c = 0; c < 64; c++){
      float xv = xp[c*TV];
      const float4* w4 = (const float4*)&w[c*48];
      #pragma unroll
      for (int o4 = 0; o4 < 12; o4++){
        float4 ww = w4[o4];
        acc[o4*4+0] += ww.x*xv; acc[o4*4+1] += ww.y*xv;
        acc[o4*4+2] += ww.z*xv; acc[o4*4+3] += ww.w*xv;
      }
    }
    #pragma unroll
    for (int o = 0; o < 48; o++){
      int l = o >> 4, oi = o & 15;
      c1[(size_t)((l*N_+n)*II + oi)*TV + rem] = acc[o];
    }
  }
  const int wv = tid >> 6, lane = tid & 63;
  #pragma unroll
  for (int o = 0; o < 48; o++){
    float s = acc[o], q = acc[o]*acc[o];
    #pragma unroll
    for (int m = 32; m; m >>= 1){ s += __shfl_xor(s, m); q += __shfl_xor(q, m); }
    if (lane == 0){ bst[wv][2*o] = s; bst[wv][2*o+1] = q; }
  }
  __syncthreads();
  float* stf = (float*)st;
  if (tid < 96) unsafeAtomicAdd(stf + tid, bst[0][tid]+bst[1][tid]+bst[2][tid]+bst[3][tid]);
}

// ---------------- K2: recompute c2[l][j] (spatial einsum + gsw conv), stats only ----------------
// Barrier-free inner loops: xdl/zz tiles are per-wave private (intra-wave LDS ordering).
__global__ __launch_bounds__(256, 4) void k2_spatial_stats(
    const float* __restrict__ c1, const float* __restrict__ PA,
    const float* __restrict__ gsw, const float* __restrict__ gsb,
    const float* __restrict__ gdg, const float* __restrict__ gdbt,
    float2* st)
{
  __shared__ float pa[5][25][28];
  __shared__ float gw[5][16][20];   // row stride 20 floats: bank-quad 2-way max (free)
  __shared__ float xdl[4][16][28];
  __shared__ float zz[4][25][20];
  __shared__ float cA[16], cB[16];
  __shared__ float bst[4][160];
  const int tid = threadIdx.x;
  const int l = blockIdx.z, n = blockIdx.y;
  for (int i = tid; i < 5*625; i += 256){ int j = i/625, r = i - j*625; pa[j][r/25][r%25] = PA[(l*5+j)*625 + r]; }
  for (int i = tid; i < 5*256; i += 256){ int j = i >> 8, r = i & 255; gw[j][r>>4][r&15] = gsw[(l*5+j)*256 + r]; }
  if (tid < 16){
    float2 ab = bncoef(st, l*16+tid, gdg[l*16+tid], gdbt[l*16+tid]);
    cA[tid] = ab.x; cB[tid] = ab.y;
  }
  __syncthreads();
  const int wv = tid >> 6, lane = tid & 63, oc = lane & 15, vg = lane >> 4;
  const int t = blockIdx.x*4 + wv;
  const float* c1p = c1 + (size_t)((l*N_+n)*II)*TV + t*25;
  for (int idx = lane; idx < 400; idx += 64){
    int c = idx/25, v = idx - c*25;
    float val = c1p[c*TV + v];
    xdl[wv][c][v] = fmaxf(cA[c]*val + cB[c], 0.f);
  }
  // intra-wave LDS RAW: no barrier needed (per-wave tile)
  float xdr[25];
  {
    const float4* xr4 = (const float4*)&xdl[wv][oc][0];
    #pragma unroll
    for (int u4 = 0; u4 < 6; u4++){
      float4 x4 = xr4[u4];
      xdr[u4*4+0]=x4.x; xdr[u4*4+1]=x4.y; xdr[u4*4+2]=x4.z; xdr[u4*4+3]=x4.w;
    }
    xdr[24] = xdl[wv][oc][24];
  }
  float sacc[5] = {0,0,0,0,0}, qacc[5] = {0,0,0,0,0};
  #pragma unroll
  for (int j = 0; j < 5; j++){
    #pragma unroll
    for (int k = 0; k < 7; k++){
      int v = vg + 4*k;
      if (v < 25){
        const float4* p4 = (const float4*)&pa[j][v][0];
        float zv = 0.f;
        #pragma unroll
        for (int u4 = 0; u4 < 6; u4++){
          float4 pp = p4[u4];
          zv += xdr[u4*4+0]*pp.x + xdr[u4*4+1]*pp.y + xdr[u4*4+2]*pp.z + xdr[u4*4+3]*pp.w;
        }
        zv += xdr[24]*pa[j][v][24];
        zz[wv][v][oc] = zv;
      }
    }
    float gwr[16];
    {
      const float4* g4 = (const float4*)&gw[j][oc][0];
      #pragma unroll
      for (int c4 = 0; c4 < 4; c4++){
        float4 gg = g4[c4];
        gwr[c4*4+0]=gg.x; gwr[c4*4+1]=gg.y; gwr[c4*4+2]=gg.z; gwr[c4*4+3]=gg.w;
      }
    }
    const float bjo = gsb[(l*5+j)*16 + oc];
    #pragma unroll
    for (int k = 0; k < 7; k++){
      int v = vg + 4*k;
      if (v < 25){
        const float4* z4 = (const float4*)&zz[wv][v][0];
        float cv = bjo;
        #pragma unroll
        for (int c4 = 0; c4 < 4; c4++){
          float4 zf = z4[c4];
          cv += gwr[c4*4+0]*zf.x + gwr[c4*4+1]*zf.y + gwr[c4*4+2]*zf.z + gwr[c4*4+3]*zf.w;
        }
        sacc[j] += cv; qacc[j] += cv*cv;
      }
    }
  }
  #pragma unroll
  for (int j = 0; j < 5; j++){
    float s = sacc[j], q = qacc[j];
    s += __shfl_xor(s,16); s += __shfl_xor(s,32);
    q += __shfl_xor(q,16); q += __shfl_xor(q,32);
    if (vg == 0){ bst[wv][2*(j*16+oc)] = s; bst[wv][2*(j*16+oc)+1] = q; }
  }
  __syncthreads();
  float* stf = (float*)st;
  for (int i = tid; i < 160; i += 256)
    unsafeAtomicAdd(stf + 96 + l*160 + i, bst[0][i]+bst[1][i]+bst[2][i]+bst[3][i]);
}

// ---------------- K3: recompute c2, apply BN, accumulate new = sum_l(ys[j]+ys[0]), stats(new) ----
__global__ __launch_bounds__(256, 3) void k3_new(
    const float* __restrict__ c1, const float* __restrict__ PA,
    const float* __restrict__ gsw, const float* __restrict__ gsb,
    const float* __restrict__ gdg, const float* __restrict__ gdbt,
    const float* __restrict__ gsg, const float* __restrict__ gsbt,
    float2* st, float* __restrict__ newb)
{
  __shared__ float pa[5][25][28];
  __shared__ float gw[5][16][20];
  __shared__ float xdl[4][16][28];
  __shared__ float zz[4][25][20];
  __shared__ float cA[16], cB[16];
  __shared__ float c2A[5][16], c2B[5][16];
  __shared__ float bst[4][128];
  const int tid = threadIdx.x;
  const int n = blockIdx.y;
  const int wv = tid >> 6, lane = tid & 63, oc = lane & 15, vg = lane >> 4;
  const int t = blockIdx.x*4 + wv;
  float newacc[4][7];
  #pragma unroll
  for (int g = 0; g < 4; g++)
    #pragma unroll
    for (int k = 0; k < 7; k++) newacc[g][k] = 0.f;

  #pragma unroll 1
  for (int l = 0; l < 3; l++){
    __syncthreads();   // WAR: previous-l readers of pa/gw/coefs done
    for (int i = tid; i < 5*625; i += 256){ int j = i/625, r = i - j*625; pa[j][r/25][r%25] = PA[(l*5+j)*625 + r]; }
    for (int i = tid; i < 5*256; i += 256){ int j = i >> 8, r = i & 255; gw[j][r>>4][r&15] = gsw[(l*5+j)*256 + r]; }
    if (tid < 16){
      float2 ab = bncoef(st, l*16+tid, gdg[l*16+tid], gdbt[l*16+tid]);
      cA[tid] = ab.x; cB[tid] = ab.y;
    }
    if (tid < 80){
      int j = tid >> 4, o = tid & 15;
      float2 ab = bncoef(st, 48 + (l*5+j)*16 + o, gsg[(l*5+j)*16+o], gsbt[(l*5+j)*16+o]);
      c2A[j][o] = ab.x; c2B[j][o] = ab.y;
    }
    __syncthreads();   // RAW: pa/gw/coefs visible to all waves
    const float* c1p = c1 + (size_t)((l*N_+n)*II)*TV + t*25;
    for (int idx = lane; idx < 400; idx += 64){
      int c = idx/25, v = idx - c*25;
      float val = c1p[c*TV + v];
      xdl[wv][c][v] = fmaxf(cA[c]*val + cB[c], 0.f);
    }
    // per-wave tile: no barrier
    float xdr[25];
    {
      const float4* xr4 = (const float4*)&xdl[wv][oc][0];
      #pragma unroll
      for (int u4 = 0; u4 < 6; u4++){
        float4 x4 = xr4[u4];
        xdr[u4*4+0]=x4.x; xdr[u4*4+1]=x4.y; xdr[u4*4+2]=x4.z; xdr[u4*4+3]=x4.w;
      }
      xdr[24] = xdl[wv][oc][24];
    }
    #pragma unroll
    for (int j = 0; j < 5; j++){
      #pragma unroll
      for (int k = 0; k < 7; k++){
        int v = vg + 4*k;
        if (v < 25){
          const float4* p4 = (const float4*)&pa[j][v][0];
          float zv = 0.f;
          #pragma unroll
          for (int u4 = 0; u4 < 6; u4++){
            float4 pp = p4[u4];
            zv += xdr[u4*4+0]*pp.x + xdr[u4*4+1]*pp.y + xdr[u4*4+2]*pp.z + xdr[u4*4+3]*pp.w;
          }
          zv += xdr[24]*pa[j][v][24];
          zz[wv][v][oc] = zv;
        }
      }
      float gwr[16];
      {
        const float4* g4 = (const float4*)&gw[j][oc][0];
        #pragma unroll
        for (int c4 = 0; c4 < 4; c4++){
          float4 gg = g4[c4];
          gwr[c4*4+0]=gg.x; gwr[c4*4+1]=gg.y; gwr[c4*4+2]=gg.z; gwr[c4*4+3]=gg.w;
        }
      }
      const float bjo = gsb[(l*5+j)*16 + oc];
      const float a2 = c2A[j][oc], b2 = c2B[j][oc];
      #pragma unroll
      for (int k = 0; k < 7; k++){
        int v = vg + 4*k;
        if (v < 25){
          const float4* z4 = (const float4*)&zz[wv][v][0];
          float cv = bjo;
          #pragma unroll
          for (int c4 = 0; c4 < 4; c4++){
            float4 zf = z4[c4];
            cv += gwr[c4*4+0]*zf.x + gwr[c4*4+1]*zf.y + gwr[c4*4+2]*zf.z + gwr[c4*4+3]*zf.w;
          }
          float yb = a2*cv + b2;
          if (j == 0){
            #pragma unroll
            for (int g = 0; g < 4; g++) newacc[g][k] += yb;
          } else {
            newacc[j-1][k] += yb;
          }
        }
      }
    }
  }
  float* np = newb + (size_t)n*64*TV + t*25;
  float sacc[4], qacc[4];
  #pragma unroll
  for (int g = 0; g < 4; g++){ sacc[g] = 0.f; qacc[g] = 0.f; }
  #pragma unroll
  for (int g = 0; g < 4; g++){
    #pragma unroll
    for (int k = 0; k < 7; k++){
      int v = vg + 4*k;
      if (v < 25){
        float val = newacc[g][k];
        np[(g*16+oc)*TV + v] = val;
        sacc[g] += val; qacc[g] += val*val;
      }
    }
  }
  #pragma unroll
  for (int g = 0; g < 4; g++){
    float s = sacc[g], q = qacc[g];
    s += __shfl_xor(s,16); s += __shfl_xor(s,32);
    q += __shfl_xor(q,16); q += __shfl_xor(q,32);
    if (vg == 0){ bst[wv][2*(g*16+oc)] = s; bst[wv][2*(g*16+oc)+1] = q; }
  }
  __syncthreads();
  float* stf = (float*)st;
  for (int i = tid; i < 128; i += 256)
    unsafeAtomicAdd(stf + 576 + i, bst[0][i]+bst[1][i]+bst[2][i]+bst[3][i]);
}

// ---------------- K4: xg = relu(bn(new)+x); y[k] = brw[k]*xg + brb[k]; stats(y) ----------------
__global__ __launch_bounds__(256) void k4_xg_branches(
    const float* __restrict__ x, const float* __restrict__ newb,
    const float* __restrict__ gbng, const float* __restrict__ gbnb,
    const float* __restrict__ brw, const float* __restrict__ brb,
    float2* st, float* __restrict__ xg, float* __restrict__ y)
{
  __shared__ float w[64*64];     // w[c*64+ko] = brw[ko*64+c]
  __shared__ float cA[64], cB[64], bias[64];
  __shared__ float bst[4][128];
  const int tid = threadIdx.x;
  for (int i = tid; i < 4096; i += 256){ int c = i >> 6, ko = i & 63; w[i] = brw[ko*64 + c]; }
  if (tid < 64){
    float2 ab = bncoef(st, 288+tid, gbng[tid], gbnb[tid]);
    cA[tid] = ab.x; cB[tid] = ab.y; bias[tid] = brb[tid];
  }
  __syncthreads();
  const int n = blockIdx.y;
  const int rem = blockIdx.x*256 + tid;
  const bool act = rem < TV;
  const float* xp  = x    + (size_t)n*64*TV + rem;
  const float* npx = newb + (size_t)n*64*TV + rem;
  float*       xgp = xg   + (size_t)n*64*TV + rem;
  float xgv[64];
  #pragma unroll
  for (int c = 0; c < 64; c++){
    float v = 0.f;
    if (act){
      v = fmaxf(cA[c]*npx[c*TV] + cB[c] + xp[c*TV], 0.f);
      xgp[c*TV] = v;
    }
    xgv[c] = v;
  }
  const int wv = tid >> 6, lane = tid & 63;
  #pragma unroll
  for (int k = 0; k < 4; k++){
    float acc[16];
    #pragma unroll
    for (int o = 0; o < 16; o++) acc[o] = act ? bias[k*16+o] : 0.f;
    #pragma unroll
    for (int c = 0; c < 64; c++){
      float xv = xgv[c];
      const float4* w4 = (const float4*)&w[c*64 + k*16];
      #pragma unroll
      for (int o4 = 0; o4 < 4; o4++){
        float4 ww = w4[o4];
        acc[o4*4+0] += ww.x*xv; acc[o4*4+1] += ww.y*xv;
        acc[o4*4+2] += ww.z*xv; acc[o4*4+3] += ww.w*xv;
      }
    }
    if (act){
      float* yp = y + (size_t)((k*N_+n)*16)*TV + rem;
      #pragma unroll
      for (int o = 0; o < 16; o++) yp[o*TV] = acc[o];
    }
    #pragma unroll
    for (int o = 0; o < 16; o++){
      float s = acc[o], q = acc[o]*acc[o];
      #pragma unroll
      for (int m = 32; m; m >>= 1){ s += __shfl_xor(s, m); q += __shfl_xor(q, m); }
      if (lane == 0){ bst[wv][2*(k*16+o)] = s; bst[wv][2*(k*16+o)+1] = q; }
    }
  }
  __syncthreads();
  float* stf = (float*)st;
  for (int i = tid; i < 128; i += 256)
    unsafeAtomicAdd(stf + 704 + i, bst[0][i]+bst[1][i]+bst[2][i]+bst[3][i]);
}

// ---------------- K5: temporal convs (d=1,2) + maxpool branch, pre-final-BN values + stats -----
__global__ __launch_bounds__(256) void k5_temporal(
    const float* __restrict__ y, const float* __restrict__ tcw, const float* __restrict__ tcbias,
    const float* __restrict__ brg, const float* __restrict__ brbt,
    float2* st, float* __restrict__ tp)
{
  __shared__ float wt[2*16*5*16];   // [k][c][ks][o]
  __shared__ float cAy[48], cBy[48];
  __shared__ float bst[4][96];
  const int tid = threadIdx.x;
  for (int i = tid; i < 2560; i += 256){
    int k = i/1280, r = i - k*1280, c = r/80, r2 = r - c*80, ks = r2 >> 4, o = r2 & 15;
    wt[i] = tcw[((k*16+o)*16 + c)*5 + ks];
  }
  if (tid < 48){
    float2 ab = bncoef(st, 352+tid, brg[tid], brbt[tid]);
    cAy[tid] = ab.x; cBy[tid] = ab.y;
  }
  __syncthreads();
  const int n = blockIdx.y;
  const int rem = blockIdx.x*256 + tid;
  const bool act = rem < TV;
  const int t = rem/25, v = rem - t*25;
  const int wv = tid >> 6, lane = tid & 63;
  #pragma unroll
  for (int k = 0; k < 2; k++){
    const int d = k + 1;
    float acc[16];
    #pragma unroll
    for (int o = 0; o < 16; o++) acc[o] = act ? tcbias[k*16+o] : 0.f;
    if (act){
      const float* yp = y + (size_t)((k*N_+n)*16)*TV;
      #pragma unroll
      for (int ks = 0; ks < 5; ks++){
        int ttt = t + d*(ks-2);
        if (ttt >= 0 && ttt < T_){
          int off = ttt*25 + v;
          #pragma unroll
          for (int c = 0; c < 16; c++){
            float val = fmaxf(cAy[k*16+c]*yp[c*TV + off] + cBy[k*16+c], 0.f);
            const float4* w4 = (const float4*)&wt[((k*16+c)*5 + ks)*16];
            #pragma unroll
            for (int o4 = 0; o4 < 4; o4++){
              float4 ww = w4[o4];
              acc[o4*4+0] += ww.x*val; acc[o4*4+1] += ww.y*val;
              acc[o4*4+2] += ww.z*val; acc[o4*4+3] += ww.w*val;
            }
          }
        }
      }
      float* op = tp + (size_t)k*6553600 + (size_t)(n*16)*TV + rem;
      #pragma unroll
      for (int o = 0; o < 16; o++) op[o*TV] = acc[o];
    }
    #pragma unroll
    for (int o = 0; o < 16; o++){
      float s = acc[o], q = acc[o]*acc[o];
      #pragma unroll
      for (int m = 32; m; m >>= 1){ s += __shfl_xor(s, m); q += __shfl_xor(q, m); }
      if (lane == 0){ bst[wv][2*(k*16+o)] = s; bst[wv][2*(k*16+o)+1] = q; }
    }
  }
  { // maxpool branch (k=2)
    float mx[16];
    #pragma unroll
    for (int o = 0; o < 16; o++) mx[o] = -1e30f;
    if (act){
      const float* yp = y + (size_t)((2*N_+n)*16)*TV;
      #pragma unroll
      for (int dt = -1; dt <= 1; dt++){
        int ttt = t + dt;
        if (ttt >= 0 && ttt < T_){
          int off = ttt*25 + v;
          #pragma unroll
          for (int o = 0; o < 16; o++){
            float val = fmaxf(cAy[32+o]*yp[o*TV + off] + cBy[32+o], 0.f);
            mx[o] = fmaxf(mx[o], val);
          }
        }
      }
      float* op = tp + (size_t)2*6553600 + (size_t)(n*16)*TV + rem;
      #pragma unroll
      for (int o = 0; o < 16; o++) op[o*TV] = mx[o];
    } else {
      #pragma unroll
      for (int o = 0; o < 16; o++) mx[o] = 0.f;
    }
    #pragma unroll
    for (int o = 0; o < 16; o++){
      float s = mx[o], q = mx[o]*mx[o];
      #pragma unroll
      for (int m = 32; m; m >>= 1){ s += __shfl_xor(s, m); q += __shfl_xor(q, m); }
      if (lane == 0){ bst[wv][64 + 2*o] = s; bst[wv][64 + 2*o + 1] = q; }
    }
  }
  __syncthreads();
  float* stf = (float*)st;
  for (int i = tid; i < 96; i += 256)
    unsafeAtomicAdd(stf + 832 + i, bst[0][i]+bst[1][i]+bst[2][i]+bst[3][i]);
}

// ---------------- K6: final BNs + concat + residual + relu ----------------
__global__ __launch_bounds__(256) void k6_final(
    const float* __restrict__ tp, const float* __restrict__ y, const float* __restrict__ xg,
    const float* __restrict__ tcg, const float* __restrict__ tcbt,
    const float* __restrict__ mpg, const float* __restrict__ mpb,
    const float* __restrict__ brg, const float* __restrict__ brbt,
    const float2* __restrict__ st, float* __restrict__ out)
{
  __shared__ float cA[64], cB[64];
  const int tid = threadIdx.x;
  if (tid < 64){
    int o = tid & 15;
    float2 ab;
    if (tid < 32)      ab = bncoef(st, 416 + tid, tcg[tid], tcbt[tid]);
    else if (tid < 48) ab = bncoef(st, 448 + o, mpg[o], mpb[o]);
    else               ab = bncoef(st, 400 + o, brg[48+o], brbt[48+o]);
    cA[tid] = ab.x; cB[tid] = ab.y;
  }
  __syncthreads();
  const int n = blockIdx.y;
  const int rem = blockIdx.x*256 + tid;
  if (rem >= TV) return;
  const float* xgp = xg + (size_t)n*64*TV + rem;
  float* op = out + (size_t)n*64*TV + rem;
  #pragma unroll
  for (int ch = 0; ch < 64; ch++){
    int o = ch & 15;
    float sv;
    if (ch < 48) sv = tp[(size_t)(ch>>4)*6553600 + (size_t)(n*16+o)*TV + rem];
    else         sv = y[(size_t)((3*N_+n)*16 + o)*TV + rem];
    float val = cA[ch]*sv + cB[ch] + xgp[ch*TV];
    op[ch*TV] = fmaxf(val, 0.f);
  }
}

extern "C" void kernel_launch(void* const* d_in, const int* in_sizes, int n_in,
                              void* d_out, int out_size, void* d_ws, size_t ws_size,
                              hipStream_t stream) {
  (void)in_sizes; (void)n_in; (void)out_size; (void)ws_size;
  const float* x    = (const float*)d_in[0];
  const float* PA   = (const float*)d_in[1];
  const float* gdw  = (const float*)d_in[2];
  const float* gdb  = (const float*)d_in[3];
  const float* gdg  = (const float*)d_in[4];
  const float* gdbt = (const float*)d_in[5];
  const float* gsw  = (const float*)d_in[6];
  const float* gsb  = (const float*)d_in[7];
  const float* gsg  = (const float*)d_in[8];
  const float* gsbt = (const float*)d_in[9];
  const float* gbng = (const float*)d_in[10];
  const float* gbnb = (const float*)d_in[11];
  const float* brw  = (const float*)d_in[12];
  const float* brb  = (const float*)d_in[13];
  const float* brg  = (const float*)d_in[14];
  const float* brbt = (const float*)d_in[15];
  const float* tcw  = (const float*)d_in[16];
  const float* tcbias=(const float*)d_in[17];
  const float* tcg  = (const float*)d_in[18];
  const float* tcbt = (const float*)d_in[19];
  const float* mpg  = (const float*)d_in[20];
  const float* mpb  = (const float*)d_in[21];

  char* ws = (char*)d_ws;
  float2* st  = (float2*)ws;                                   // 4 KB stats
  float* c1   = (float*)(ws + 4096);                           // 78.6 MB (reused as tp later)
  float* tp   = c1;
  float* newb = (float*)(ws + 4096 + 78643200);                // 104.9 MB
  float* xg   = (float*)(ws + 4096 + 78643200 + 104857600);    // 104.9 MB
  float* y    = (float*)(ws + 4096 + 78643200 + 209715200);    // 104.9 MB

  hipMemsetAsync(st, 0, 4096, stream);
  dim3 b(256);
  k1_conv_dw     <<<dim3(13,128),   b, 0, stream>>>(x, gdw, gdb, c1, st);
  k2_spatial_stats<<<dim3(32,128,3), b, 0, stream>>>(c1, PA, gsw, gsb, gdg, gdbt, st);
  k3_new         <<<dim3(32,128),   b, 0, stream>>>(c1, PA, gsw, gsb, gdg, gdbt, gsg, gsbt, st, newb);
  k4_xg_branches <<<dim3(13,128),   b, 0, stream>>>(x, newb, gbng, gbnb, brw, brb, st, xg, y);
  k5_temporal    <<<dim3(13,128),   b, 0, stream>>>(y, tcw, tcbias, brg, brbt, st, tp);
  k6_final       <<<dim3(13,128),   b, 0, stream>>>(tp, y, xg, tcg, tcbt, mpg, mpb, brg, brbt, st, (float*)d_out);
}

// Round 3
// 2277.109 us; speedup vs baseline: 1.8104x; 1.8104x over previous
//
#include <hip/hip_runtime.h>

#define N_ 128
#define T_ 128
#define V_ 25
#define TV 3200
#define LL 3
#define SS 5
#define II 16
#define EPSB 1e-5f
#define MCNT 409600.0f

// stats float2 slots: c1:[0,48) c2:[48,288) new:[288,352) y:[352,416) t:[416,448) p:[448,464)

__device__ __forceinline__ float2 bncoef(const float2* st, int slot, float g, float bt){
  float2 s = st[slot];
  float m  = s.x * (1.0f/MCNT);
  float var = s.y * (1.0f/MCNT) - m*m;
  float a = g * rsqrtf(var + EPSB);
  return make_float2(a, bt - m*a);
}

// ---------------- K1: c1[l] = x * gdw[l]^T + gdb[l]  (48 out channels), + stats ----------------
__global__ __launch_bounds__(256) void k1_conv_dw(
    const float* __restrict__ x, const float* __restrict__ gdw, const float* __restrict__ gdb,
    float* __restrict__ c1, float2* st)
{
  __shared__ float w[64*48];      // w[c*48+o] = gdw[o*64+c]
  __shared__ float bias[48];
  __shared__ float bst[4][96];
  const int tid = threadIdx.x;
  for (int i = tid; i < 64*48; i += 256){ int c = i/48, o = i - c*48; w[i] = gdw[o*64 + c]; }
  if (tid < 48) bias[tid] = gdb[tid];
  __syncthreads();
  const int n = blockIdx.y;
  const int rem = blockIdx.x*256 + tid;
  const bool act = rem < TV;
  float acc[48];
  #pragma unroll
  for (int o = 0; o < 48; o++) acc[o] = act ? bias[o] : 0.f;
  const float* xp = x + (size_t)n*64*TV + rem;
  if (act){
    #pragma unroll 4
    for (int c = 0; c < 64; c++){
      float xv = xp[c*TV];
      const float4* w4 = (const float4*)&w[c*48];
      #pragma unroll
      for (int o4 = 0; o4 < 12; o4++){
        float4 ww = w4[o4];
        acc[o4*4+0] += ww.x*xv; acc[o4*4+1] += ww.y*xv;
        acc[o4*4+2] += ww.z*xv; acc[o4*4+3] += ww.w*xv;
      }
    }
    #pragma unroll
    for (int o = 0; o < 48; o++){
      int l = o >> 4, oi = o & 15;
      c1[(size_t)((l*N_+n)*II + oi)*TV + rem] = acc[o];
    }
  }
  const int wv = tid >> 6, lane = tid & 63;
  #pragma unroll
  for (int o = 0; o < 48; o++){
    float s = acc[o], q = acc[o]*acc[o];
    #pragma unroll
    for (int m = 32; m; m >>= 1){ s += __shfl_xor(s, m); q += __shfl_xor(q, m); }
    if (lane == 0){ bst[wv][2*o] = s; bst[wv][2*o+1] = q; }
  }
  __syncthreads();
  float* stf = (float*)st;
  if (tid < 96) unsafeAtomicAdd(stf + tid, bst[0][tid]+bst[1][tid]+bst[2][tid]+bst[3][tid]);
}

// ---------------- K2: recompute c2[l][j] (spatial einsum + gsw conv), stats only ----------------
// Barrier-free inner loops: xdl/zz tiles are per-wave private (intra-wave LDS ordering).
// NO min-waves launch bound: a VGPR cap here spills the unrolled accumulators to scratch
// (round 2: 9.8 GB of spill traffic on k3, VALUBusy 7%). Let the allocator have what it needs.
__global__ __launch_bounds__(256) void k2_spatial_stats(
    const float* __restrict__ c1, const float* __restrict__ PA,
    const float* __restrict__ gsw, const float* __restrict__ gsb,
    const float* __restrict__ gdg, const float* __restrict__ gdbt,
    float2* st)
{
  __shared__ float pa[5][25][28];
  __shared__ float gw[5][16][20];   // row stride 20 floats: bank-quad 2-way max (free)
  __shared__ float xdl[4][16][28];
  __shared__ float zz[4][25][20];
  __shared__ float cA[16], cB[16];
  __shared__ float bst[4][160];
  const int tid = threadIdx.x;
  const int l = blockIdx.z, n = blockIdx.y;
  for (int i = tid; i < 5*625; i += 256){ int j = i/625, r = i - j*625; pa[j][r/25][r%25] = PA[(l*5+j)*625 + r]; }
  for (int i = tid; i < 5*256; i += 256){ int j = i >> 8, r = i & 255; gw[j][r>>4][r&15] = gsw[(l*5+j)*256 + r]; }
  if (tid < 16){
    float2 ab = bncoef(st, l*16+tid, gdg[l*16+tid], gdbt[l*16+tid]);
    cA[tid] = ab.x; cB[tid] = ab.y;
  }
  __syncthreads();
  const int wv = tid >> 6, lane = tid & 63, oc = lane & 15, vg = lane >> 4;
  const int t = blockIdx.x*4 + wv;
  const float* c1p = c1 + (size_t)((l*N_+n)*II)*TV + t*25;
  for (int idx = lane; idx < 400; idx += 64){
    int c = idx/25, v = idx - c*25;
    float val = c1p[c*TV + v];
    xdl[wv][c][v] = fmaxf(cA[c]*val + cB[c], 0.f);
  }
  // intra-wave LDS RAW: no barrier needed (per-wave tile)
  float xdr[25];
  {
    const float4* xr4 = (const float4*)&xdl[wv][oc][0];
    #pragma unroll
    for (int u4 = 0; u4 < 6; u4++){
      float4 x4 = xr4[u4];
      xdr[u4*4+0]=x4.x; xdr[u4*4+1]=x4.y; xdr[u4*4+2]=x4.z; xdr[u4*4+3]=x4.w;
    }
    xdr[24] = xdl[wv][oc][24];
  }
  float sacc[5] = {0,0,0,0,0}, qacc[5] = {0,0,0,0,0};
  #pragma unroll
  for (int j = 0; j < 5; j++){
    #pragma unroll
    for (int k = 0; k < 7; k++){
      int v = vg + 4*k;
      if (v < 25){
        const float4* p4 = (const float4*)&pa[j][v][0];
        float zv = 0.f;
        #pragma unroll
        for (int u4 = 0; u4 < 6; u4++){
          float4 pp = p4[u4];
          zv += xdr[u4*4+0]*pp.x + xdr[u4*4+1]*pp.y + xdr[u4*4+2]*pp.z + xdr[u4*4+3]*pp.w;
        }
        zv += xdr[24]*pa[j][v][24];
        zz[wv][v][oc] = zv;
      }
    }
    float gwr[16];
    {
      const float4* g4 = (const float4*)&gw[j][oc][0];
      #pragma unroll
      for (int c4 = 0; c4 < 4; c4++){
        float4 gg = g4[c4];
        gwr[c4*4+0]=gg.x; gwr[c4*4+1]=gg.y; gwr[c4*4+2]=gg.z; gwr[c4*4+3]=gg.w;
      }
    }
    const float bjo = gsb[(l*5+j)*16 + oc];
    #pragma unroll
    for (int k = 0; k < 7; k++){
      int v = vg + 4*k;
      if (v < 25){
        const float4* z4 = (const float4*)&zz[wv][v][0];
        float cv = bjo;
        #pragma unroll
        for (int c4 = 0; c4 < 4; c4++){
          float4 zf = z4[c4];
          cv += gwr[c4*4+0]*zf.x + gwr[c4*4+1]*zf.y + gwr[c4*4+2]*zf.z + gwr[c4*4+3]*zf.w;
        }
        sacc[j] += cv; qacc[j] += cv*cv;
      }
    }
  }
  #pragma unroll
  for (int j = 0; j < 5; j++){
    float s = sacc[j], q = qacc[j];
    s += __shfl_xor(s,16); s += __shfl_xor(s,32);
    q += __shfl_xor(q,16); q += __shfl_xor(q,32);
    if (vg == 0){ bst[wv][2*(j*16+oc)] = s; bst[wv][2*(j*16+oc)+1] = q; }
  }
  __syncthreads();
  float* stf = (float*)st;
  for (int i = tid; i < 160; i += 256)
    unsafeAtomicAdd(stf + 96 + l*160 + i, bst[0][i]+bst[1][i]+bst[2][i]+bst[3][i]);
}

// ---------------- K3: recompute c2, apply BN, accumulate new = sum_l(ys[j]+ys[0]), stats(new) ----
// Same skeleton as K2; l-loop NOT unrolled (register pressure), no VGPR cap (spill avoidance).
__global__ __launch_bounds__(256) void k3_new(
    const float* __restrict__ c1, const float* __restrict__ PA,
    const float* __restrict__ gsw, const float* __restrict__ gsb,
    const float* __restrict__ gdg, const float* __restrict__ gdbt,
    const float* __restrict__ gsg, const float* __restrict__ gsbt,
    float2* st, float* __restrict__ newb)
{
  __shared__ float pa[5][25][28];
  __shared__ float gw[5][16][20];
  __shared__ float xdl[4][16][28];
  __shared__ float zz[4][25][20];
  __shared__ float cA[16], cB[16];
  __shared__ float c2A[5][16], c2B[5][16];
  __shared__ float bst[4][128];
  const int tid = threadIdx.x;
  const int n = blockIdx.y;
  const int wv = tid >> 6, lane = tid & 63, oc = lane & 15, vg = lane >> 4;
  const int t = blockIdx.x*4 + wv;
  float newacc[4][7];
  #pragma unroll
  for (int g = 0; g < 4; g++)
    #pragma unroll
    for (int k = 0; k < 7; k++) newacc[g][k] = 0.f;

  #pragma unroll 1
  for (int l = 0; l < 3; l++){
    __syncthreads();   // WAR: previous-l readers of pa/gw/coefs done
    for (int i = tid; i < 5*625; i += 256){ int j = i/625, r = i - j*625; pa[j][r/25][r%25] = PA[(l*5+j)*625 + r]; }
    for (int i = tid; i < 5*256; i += 256){ int j = i >> 8, r = i & 255; gw[j][r>>4][r&15] = gsw[(l*5+j)*256 + r]; }
    if (tid < 16){
      float2 ab = bncoef(st, l*16+tid, gdg[l*16+tid], gdbt[l*16+tid]);
      cA[tid] = ab.x; cB[tid] = ab.y;
    }
    if (tid < 80){
      int j = tid >> 4, o = tid & 15;
      float2 ab = bncoef(st, 48 + (l*5+j)*16 + o, gsg[(l*5+j)*16+o], gsbt[(l*5+j)*16+o]);
      c2A[j][o] = ab.x; c2B[j][o] = ab.y;
    }
    __syncthreads();   // RAW: pa/gw/coefs visible to all waves
    const float* c1p = c1 + (size_t)((l*N_+n)*II)*TV + t*25;
    for (int idx = lane; idx < 400; idx += 64){
      int c = idx/25, v = idx - c*25;
      float val = c1p[c*TV + v];
      xdl[wv][c][v] = fmaxf(cA[c]*val + cB[c], 0.f);
    }
    // per-wave tile: no barrier
    float xdr[25];
    {
      const float4* xr4 = (const float4*)&xdl[wv][oc][0];
      #pragma unroll
      for (int u4 = 0; u4 < 6; u4++){
        float4 x4 = xr4[u4];
        xdr[u4*4+0]=x4.x; xdr[u4*4+1]=x4.y; xdr[u4*4+2]=x4.z; xdr[u4*4+3]=x4.w;
      }
      xdr[24] = xdl[wv][oc][24];
    }
    #pragma unroll
    for (int j = 0; j < 5; j++){
      #pragma unroll
      for (int k = 0; k < 7; k++){
        int v = vg + 4*k;
        if (v < 25){
          const float4* p4 = (const float4*)&pa[j][v][0];
          float zv = 0.f;
          #pragma unroll
          for (int u4 = 0; u4 < 6; u4++){
            float4 pp = p4[u4];
            zv += xdr[u4*4+0]*pp.x + xdr[u4*4+1]*pp.y + xdr[u4*4+2]*pp.z + xdr[u4*4+3]*pp.w;
          }
          zv += xdr[24]*pa[j][v][24];
          zz[wv][v][oc] = zv;
        }
      }
      float gwr[16];
      {
        const float4* g4 = (const float4*)&gw[j][oc][0];
        #pragma unroll
        for (int c4 = 0; c4 < 4; c4++){
          float4 gg = g4[c4];
          gwr[c4*4+0]=gg.x; gwr[c4*4+1]=gg.y; gwr[c4*4+2]=gg.z; gwr[c4*4+3]=gg.w;
        }
      }
      const float bjo = gsb[(l*5+j)*16 + oc];
      const float a2 = c2A[j][oc], b2 = c2B[j][oc];
      #pragma unroll
      for (int k = 0; k < 7; k++){
        int v = vg + 4*k;
        if (v < 25){
          const float4* z4 = (const float4*)&zz[wv][v][0];
          float cv = bjo;
          #pragma unroll
          for (int c4 = 0; c4 < 4; c4++){
            float4 zf = z4[c4];
            cv += gwr[c4*4+0]*zf.x + gwr[c4*4+1]*zf.y + gwr[c4*4+2]*zf.z + gwr[c4*4+3]*zf.w;
          }
          float yb = a2*cv + b2;
          if (j == 0){
            #pragma unroll
            for (int g = 0; g < 4; g++) newacc[g][k] += yb;
          } else {
            newacc[j-1][k] += yb;
          }
        }
      }
    }
  }
  float* np = newb + (size_t)n*64*TV + t*25;
  float sacc[4], qacc[4];
  #pragma unroll
  for (int g = 0; g < 4; g++){ sacc[g] = 0.f; qacc[g] = 0.f; }
  #pragma unroll
  for (int g = 0; g < 4; g++){
    #pragma unroll
    for (int k = 0; k < 7; k++){
      int v = vg + 4*k;
      if (v < 25){
        float val = newacc[g][k];
        np[(g*16+oc)*TV + v] = val;
        sacc[g] += val; qacc[g] += val*val;
      }
    }
  }
  #pragma unroll
  for (int g = 0; g < 4; g++){
    float s = sacc[g], q = qacc[g];
    s += __shfl_xor(s,16); s += __shfl_xor(s,32);
    q += __shfl_xor(q,16); q += __shfl_xor(q,32);
    if (vg == 0){ bst[wv][2*(g*16+oc)] = s; bst[wv][2*(g*16+oc)+1] = q; }
  }
  __syncthreads();
  float* stf = (float*)st;
  for (int i = tid; i < 128; i += 256)
    unsafeAtomicAdd(stf + 576 + i, bst[0][i]+bst[1][i]+bst[2][i]+bst[3][i]);
}

// ---------------- K4: xg = relu(bn(new)+x); y[k] = brw[k]*xg + brb[k]; stats(y) ----------------
__global__ __launch_bounds__(256) void k4_xg_branches(
    const float* __restrict__ x, const float* __restrict__ newb,
    const float* __restrict__ gbng, const float* __restrict__ gbnb,
    const float* __restrict__ brw, const float* __restrict__ brb,
    float2* st, float* __restrict__ xg, float* __restrict__ y)
{
  __shared__ float w[64*64];     // w[c*64+ko] = brw[ko*64+c]
  __shared__ float cA[64], cB[64], bias[64];
  __shared__ float bst[4][128];
  const int tid = threadIdx.x;
  for (int i = tid; i < 4096; i += 256){ int c = i >> 6, ko = i & 63; w[i] = brw[ko*64 + c]; }
  if (tid < 64){
    float2 ab = bncoef(st, 288+tid, gbng[tid], gbnb[tid]);
    cA[tid] = ab.x; cB[tid] = ab.y; bias[tid] = brb[tid];
  }
  __syncthreads();
  const int n = blockIdx.y;
  const int rem = blockIdx.x*256 + tid;
  const bool act = rem < TV;
  const float* xp  = x    + (size_t)n*64*TV + rem;
  const float* npx = newb + (size_t)n*64*TV + rem;
  float*       xgp = xg   + (size_t)n*64*TV + rem;
  float xgv[64];
  #pragma unroll
  for (int c = 0; c < 64; c++){
    float v = 0.f;
    if (act){
      v = fmaxf(cA[c]*npx[c*TV] + cB[c] + xp[c*TV], 0.f);
      xgp[c*TV] = v;
    }
    xgv[c] = v;
  }
  const int wv = tid >> 6, lane = tid & 63;
  #pragma unroll
  for (int k = 0; k < 4; k++){
    float acc[16];
    #pragma unroll
    for (int o = 0; o < 16; o++) acc[o] = act ? bias[k*16+o] : 0.f;
    #pragma unroll
    for (int c = 0; c < 64; c++){
      float xv = xgv[c];
      const float4* w4 = (const float4*)&w[c*64 + k*16];
      #pragma unroll
      for (int o4 = 0; o4 < 4; o4++){
        float4 ww = w4[o4];
        acc[o4*4+0] += ww.x*xv; acc[o4*4+1] += ww.y*xv;
        acc[o4*4+2] += ww.z*xv; acc[o4*4+3] += ww.w*xv;
      }
    }
    if (act){
      float* yp = y + (size_t)((k*N_+n)*16)*TV + rem;
      #pragma unroll
      for (int o = 0; o < 16; o++) yp[o*TV] = acc[o];
    }
    #pragma unroll
    for (int o = 0; o < 16; o++){
      float s = acc[o], q = acc[o]*acc[o];
      #pragma unroll
      for (int m = 32; m; m >>= 1){ s += __shfl_xor(s, m); q += __shfl_xor(q, m); }
      if (lane == 0){ bst[wv][2*(k*16+o)] = s; bst[wv][2*(k*16+o)+1] = q; }
    }
  }
  __syncthreads();
  float* stf = (float*)st;
  for (int i = tid; i < 128; i += 256)
    unsafeAtomicAdd(stf + 704 + i, bst[0][i]+bst[1][i]+bst[2][i]+bst[3][i]);
}

// ---------------- K5: temporal convs (d=1,2) + maxpool branch, pre-final-BN values + stats -----
__global__ __launch_bounds__(256) void k5_temporal(
    const float* __restrict__ y, const float* __restrict__ tcw, const float* __restrict__ tcbias,
    const float* __restrict__ brg, const float* __restrict__ brbt,
    float2* st, float* __restrict__ tp)
{
  __shared__ float wt[2*16*5*16];   // [k][c][ks][o]
  __shared__ float cAy[48], cBy[48];
  __shared__ float bst[4][96];
  const int tid = threadIdx.x;
  for (int i = tid; i < 2560; i += 256){
    int k = i/1280, r = i - k*1280, c = r/80, r2 = r - c*80, ks = r2 >> 4, o = r2 & 15;
    wt[i] = tcw[((k*16+o)*16 + c)*5 + ks];
  }
  if (tid < 48){
    float2 ab = bncoef(st, 352+tid, brg[tid], brbt[tid]);
    cAy[tid] = ab.x; cBy[tid] = ab.y;
  }
  __syncthreads();
  const int n = blockIdx.y;
  const int rem = blockIdx.x*256 + tid;
  const bool act = rem < TV;
  const int t = rem/25, v = rem - t*25;
  const int wv = tid >> 6, lane = tid & 63;
  #pragma unroll
  for (int k = 0; k < 2; k++){
    const int d = k + 1;
    float acc[16];
    #pragma unroll
    for (int o = 0; o < 16; o++) acc[o] = act ? tcbias[k*16+o] : 0.f;
    if (act){
      const float* yp = y + (size_t)((k*N_+n)*16)*TV;
      #pragma unroll
      for (int ks = 0; ks < 5; ks++){
        int ttt = t + d*(ks-2);
        if (ttt >= 0 && ttt < T_){
          int off = ttt*25 + v;
          #pragma unroll
          for (int c = 0; c < 16; c++){
            float val = fmaxf(cAy[k*16+c]*yp[c*TV + off] + cBy[k*16+c], 0.f);
            const float4* w4 = (const float4*)&wt[((k*16+c)*5 + ks)*16];
            #pragma unroll
            for (int o4 = 0; o4 < 4; o4++){
              float4 ww = w4[o4];
              acc[o4*4+0] += ww.x*val; acc[o4*4+1] += ww.y*val;
              acc[o4*4+2] += ww.z*val; acc[o4*4+3] += ww.w*val;
            }
          }
        }
      }
      float* op = tp + (size_t)k*6553600 + (size_t)(n*16)*TV + rem;
      #pragma unroll
      for (int o = 0; o < 16; o++) op[o*TV] = acc[o];
    }
    #pragma unroll
    for (int o = 0; o < 16; o++){
      float s = acc[o], q = acc[o]*acc[o];
      #pragma unroll
      for (int m = 32; m; m >>= 1){ s += __shfl_xor(s, m); q += __shfl_xor(q, m); }
      if (lane == 0){ bst[wv][2*(k*16+o)] = s; bst[wv][2*(k*16+o)+1] = q; }
    }
  }
  { // maxpool branch (k=2)
    float mx[16];
    #pragma unroll
    for (int o = 0; o < 16; o++) mx[o] = -1e30f;
    if (act){
      const float* yp = y + (size_t)((2*N_+n)*16)*TV;
      #pragma unroll
      for (int dt = -1; dt <= 1; dt++){
        int ttt = t + dt;
        if (ttt >= 0 && ttt < T_){
          int off = ttt*25 + v;
          #pragma unroll
          for (int o = 0; o < 16; o++){
            float val = fmaxf(cAy[32+o]*yp[o*TV + off] + cBy[32+o], 0.f);
            mx[o] = fmaxf(mx[o], val);
          }
        }
      }
      float* op = tp + (size_t)2*6553600 + (size_t)(n*16)*TV + rem;
      #pragma unroll
      for (int o = 0; o < 16; o++) op[o*TV] = mx[o];
    } else {
      #pragma unroll
      for (int o = 0; o < 16; o++) mx[o] = 0.f;
    }
    #pragma unroll
    for (int o = 0; o < 16; o++){
      float s = mx[o], q = mx[o]*mx[o];
      #pragma unroll
      for (int m = 32; m; m >>= 1){ s += __shfl_xor(s, m); q += __shfl_xor(q, m); }
      if (lane == 0){ bst[wv][64 + 2*o] = s; bst[wv][64 + 2*o + 1] = q; }
    }
  }
  __syncthreads();
  float* stf = (float*)st;
  for (int i = tid; i < 96; i += 256)
    unsafeAtomicAdd(stf + 832 + i, bst[0][i]+bst[1][i]+bst[2][i]+bst[3][i]);
}

// ---------------- K6: final BNs + concat + residual + relu ----------------
__global__ __launch_bounds__(256) void k6_final(
    const float* __restrict__ tp, const float* __restrict__ y, const float* __restrict__ xg,
    const float* __restrict__ tcg, const float* __restrict__ tcbt,
    const float* __restrict__ mpg, const float* __restrict__ mpb,
    const float* __restrict__ brg, const float* __restrict__ brbt,
    const float2* __restrict__ st, float* __restrict__ out)
{
  __shared__ float cA[64], cB[64];
  const int tid = threadIdx.x;
  if (tid < 64){
    int o = tid & 15;
    float2 ab;
    if (tid < 32)      ab = bncoef(st, 416 + tid, tcg[tid], tcbt[tid]);
    else if (tid < 48) ab = bncoef(st, 448 + o, mpg[o], mpb[o]);
    else               ab = bncoef(st, 400 + o, brg[48+o], brbt[48+o]);
    cA[tid] = ab.x; cB[tid] = ab.y;
  }
  __syncthreads();
  const int n = blockIdx.y;
  const int rem = blockIdx.x*256 + tid;
  if (rem >= TV) return;
  const float* xgp = xg + (size_t)n*64*TV + rem;
  float* op = out + (size_t)n*64*TV + rem;
  #pragma unroll
  for (int ch = 0; ch < 64; ch++){
    int o = ch & 15;
    float sv;
    if (ch < 48) sv = tp[(size_t)(ch>>4)*6553600 + (size_t)(n*16+o)*TV + rem];
    else         sv = y[(size_t)((3*N_+n)*16 + o)*TV + rem];
    float val = cA[ch]*sv + cB[ch] + xgp[ch*TV];
    op[ch*TV] = fmaxf(val, 0.f);
  }
}

extern "C" void kernel_launch(void* const* d_in, const int* in_sizes, int n_in,
                              void* d_out, int out_size, void* d_ws, size_t ws_size,
                              hipStream_t stream) {
  (void)in_sizes; (void)n_in; (void)out_size; (void)ws_size;
  const float* x    = (const float*)d_in[0];
  const float* PA   = (const float*)d_in[1];
  const float* gdw  = (const float*)d_in[2];
  const float* gdb  = (const float*)d_in[3];
  const float* gdg  = (const float*)d_in[4];
  const float* gdbt = (const float*)d_in[5];
  const float* gsw  = (const float*)d_in[6];
  const float* gsb  = (const float*)d_in[7];
  const float* gsg  = (const float*)d_in[8];
  const float* gsbt = (const float*)d_in[9];
  const float* gbng = (const float*)d_in[10];
  const float* gbnb = (const float*)d_in[11];
  const float* brw  = (const float*)d_in[12];
  const float* brb  = (const float*)d_in[13];
  const float* brg  = (const float*)d_in[14];
  const float* brbt = (const float*)d_in[15];
  const float* tcw  = (const float*)d_in[16];
  const float* tcbias=(const float*)d_in[17];
  const float* tcg  = (const float*)d_in[18];
  const float* tcbt = (const float*)d_in[19];
  const float* mpg  = (const float*)d_in[20];
  const float* mpb  = (const float*)d_in[21];

  char* ws = (char*)d_ws;
  float2* st  = (float2*)ws;                                   // 4 KB stats
  float* c1   = (float*)(ws + 4096);                           // 78.6 MB (reused as tp later)
  float* tp   = c1;
  float* newb = (float*)(ws + 4096 + 78643200);                // 104.9 MB
  float* xg   = (float*)(ws + 4096 + 78643200 + 104857600);    // 104.9 MB
  float* y    = (float*)(ws + 4096 + 78643200 + 209715200);    // 104.9 MB

  hipMemsetAsync(st, 0, 4096, stream);
  dim3 b(256);
  k1_conv_dw     <<<dim3(13,128),   b, 0, stream>>>(x, gdw, gdb, c1, st);
  k2_spatial_stats<<<dim3(32,128,3), b, 0, stream>>>(c1, PA, gsw, gsb, gdg, gdbt, st);
  k3_new         <<<dim3(32,128),   b, 0, stream>>>(c1, PA, gsw, gsb, gdg, gdbt, gsg, gsbt, st, newb);
  k4_xg_branches <<<dim3(13,128),   b, 0, stream>>>(x, newb, gbng, gbnb, brw, brb, st, xg, y);
  k5_temporal    <<<dim3(13,128),   b, 0, stream>>>(y, tcw, tcbias, brg, brbt, st, tp);
  k6_final       <<<dim3(13,128),   b, 0, stream>>>(tp, y, xg, tcg, tcbt, mpg, mpb, brg, brbt, st, (float*)d_out);
}

// Round 4
// 1398.711 us; speedup vs baseline: 2.9473x; 1.6280x over previous
//
#include <hip/hip_runtime.h>

#define N_ 128
#define T_ 128
#define V_ 25
#define TV 3200
#define LL 3
#define SS 5
#define II 16
#define EPSB 1e-5f
#define MCNT 409600.0f

// stats float2 slots: c1:[0,48) c2:[48,288) new:[288,352) y:[352,416) t:[416,448) p:[448,464)

__device__ __forceinline__ float2 bncoef(const float2* st, int slot, float g, float bt){
  float2 s = st[slot];
  float m  = s.x * (1.0f/MCNT);
  float var = s.y * (1.0f/MCNT) - m*m;
  float a = g * rsqrtf(var + EPSB);
  return make_float2(a, bt - m*a);
}

// ---------------- K1: c1[l] = x * gdw[l]^T + gdb[l]  (48 out channels), + stats ----------------
__global__ __launch_bounds__(256) void k1_conv_dw(
    const float* __restrict__ x, const float* __restrict__ gdw, const float* __restrict__ gdb,
    float* __restrict__ c1, float2* st)
{
  __shared__ float w[64*48];      // w[c*48+o] = gdw[o*64+c]
  __shared__ float bias[48];
  __shared__ float bst[4][96];
  const int tid = threadIdx.x;
  for (int i = tid; i < 64*48; i += 256){ int c = i/48, o = i - c*48; w[i] = gdw[o*64 + c]; }
  if (tid < 48) bias[tid] = gdb[tid];
  __syncthreads();
  const int n = blockIdx.y;
  const int rem = blockIdx.x*256 + tid;
  const bool act = rem < TV;
  float acc[48];
  #pragma unroll
  for (int o = 0; o < 48; o++) acc[o] = act ? bias[o] : 0.f;
  const float* xp = x + (size_t)n*64*TV + rem;
  if (act){
    #pragma unroll 4
    for (int c = 0; c < 64; c++){
      float xv = xp[c*TV];
      const float4* w4 = (const float4*)&w[c*48];
      #pragma unroll
      for (int o4 = 0; o4 < 12; o4++){
        float4 ww = w4[o4];
        acc[o4*4+0] += ww.x*xv; acc[o4*4+1] += ww.y*xv;
        acc[o4*4+2] += ww.z*xv; acc[o4*4+3] += ww.w*xv;
      }
    }
    #pragma unroll
    for (int o = 0; o < 48; o++){
      int l = o >> 4, oi = o & 15;
      c1[(size_t)((l*N_+n)*II + oi)*TV + rem] = acc[o];
    }
  }
  const int wv = tid >> 6, lane = tid & 63;
  #pragma unroll
  for (int o = 0; o < 48; o++){
    float s = acc[o], q = acc[o]*acc[o];
    #pragma unroll
    for (int m = 32; m; m >>= 1){ s += __shfl_xor(s, m); q += __shfl_xor(q, m); }
    if (lane == 0){ bst[wv][2*o] = s; bst[wv][2*o+1] = q; }
  }
  __syncthreads();
  float* stf = (float*)st;
  if (tid < 96) unsafeAtomicAdd(stf + tid, bst[0][tid]+bst[1][tid]+bst[2][tid]+bst[3][tid]);
}

// ---------------- K2: recompute c2[l][j] (spatial einsum + gsw conv), stats only ----------------
// j-loop NOT unrolled (#pragma unroll 1): bounds the scheduler's live window so the 42
// float4 pa-loads per j don't all get hoisted (round-3 k3: VGPR=256 + 1.7GB spill writes).
// Stats reduced to scalars inside the loop (no runtime-indexed register arrays, rule #20).
__global__ __launch_bounds__(256) void k2_spatial_stats(
    const float* __restrict__ c1, const float* __restrict__ PA,
    const float* __restrict__ gsw, const float* __restrict__ gsb,
    const float* __restrict__ gdg, const float* __restrict__ gdbt,
    float2* st)
{
  __shared__ float pa[5][25][28];
  __shared__ float gw[5][16][20];   // row stride 20 floats: bank-quad 2-way max (free)
  __shared__ float xdl[4][16][28];
  __shared__ float zz[4][25][20];
  __shared__ float cA[16], cB[16];
  __shared__ float bst[4][160];
  const int tid = threadIdx.x;
  const int l = blockIdx.z, n = blockIdx.y;
  for (int i = tid; i < 5*625; i += 256){ int j = i/625, r = i - j*625; pa[j][r/25][r%25] = PA[(l*5+j)*625 + r]; }
  for (int i = tid; i < 5*256; i += 256){ int j = i >> 8, r = i & 255; gw[j][r>>4][r&15] = gsw[(l*5+j)*256 + r]; }
  if (tid < 16){
    float2 ab = bncoef(st, l*16+tid, gdg[l*16+tid], gdbt[l*16+tid]);
    cA[tid] = ab.x; cB[tid] = ab.y;
  }
  __syncthreads();
  const int wv = tid >> 6, lane = tid & 63, oc = lane & 15, vg = lane >> 4;
  const int t = blockIdx.x*4 + wv;
  const float* c1p = c1 + (size_t)((l*N_+n)*II)*TV + t*25;
  for (int idx = lane; idx < 400; idx += 64){
    int c = idx/25, v = idx - c*25;
    float val = c1p[c*TV + v];
    xdl[wv][c][v] = fmaxf(cA[c]*val + cB[c], 0.f);
  }
  // intra-wave LDS RAW: no barrier needed (per-wave tile)
  float xdr[25];
  {
    const float4* xr4 = (const float4*)&xdl[wv][oc][0];
    #pragma unroll
    for (int u4 = 0; u4 < 6; u4++){
      float4 x4 = xr4[u4];
      xdr[u4*4+0]=x4.x; xdr[u4*4+1]=x4.y; xdr[u4*4+2]=x4.z; xdr[u4*4+3]=x4.w;
    }
    xdr[24] = xdl[wv][oc][24];
  }
  #pragma unroll 1
  for (int j = 0; j < 5; j++){
    #pragma unroll
    for (int k = 0; k < 7; k++){
      int v = vg + 4*k;
      if (v < 25){
        const float4* p4 = (const float4*)&pa[j][v][0];
        float zv = 0.f;
        #pragma unroll
        for (int u4 = 0; u4 < 6; u4++){
          float4 pp = p4[u4];
          zv += xdr[u4*4+0]*pp.x + xdr[u4*4+1]*pp.y + xdr[u4*4+2]*pp.z + xdr[u4*4+3]*pp.w;
        }
        zv += xdr[24]*pa[j][v][24];
        zz[wv][v][oc] = zv;
      }
    }
    float gwr[16];
    {
      const float4* g4 = (const float4*)&gw[j][oc][0];
      #pragma unroll
      for (int c4 = 0; c4 < 4; c4++){
        float4 gg = g4[c4];
        gwr[c4*4+0]=gg.x; gwr[c4*4+1]=gg.y; gwr[c4*4+2]=gg.z; gwr[c4*4+3]=gg.w;
      }
    }
    const float bjo = gsb[(l*5+j)*16 + oc];
    float s = 0.f, q = 0.f;
    #pragma unroll
    for (int k = 0; k < 7; k++){
      int v = vg + 4*k;
      if (v < 25){
        const float4* z4 = (const float4*)&zz[wv][v][0];
        float cv = bjo;
        #pragma unroll
        for (int c4 = 0; c4 < 4; c4++){
          float4 zf = z4[c4];
          cv += gwr[c4*4+0]*zf.x + gwr[c4*4+1]*zf.y + gwr[c4*4+2]*zf.z + gwr[c4*4+3]*zf.w;
        }
        s += cv; q += cv*cv;
      }
    }
    // per-j wave reduction over vg (stats are per output channel oc)
    s += __shfl_xor(s,16); s += __shfl_xor(s,32);
    q += __shfl_xor(q,16); q += __shfl_xor(q,32);
    if (vg == 0){ bst[wv][2*(j*16+oc)] = s; bst[wv][2*(j*16+oc)+1] = q; }
  }
  __syncthreads();
  float* stf = (float*)st;
  for (int i = tid; i < 160; i += 256)
    unsafeAtomicAdd(stf + 96 + l*160 + i, bst[0][i]+bst[1][i]+bst[2][i]+bst[3][i]);
}

// ---------------- K3: recompute c2, apply BN, accumulate new = sum_l(ys[j]+ys[0]), stats(new) ----
// j-loop NOT unrolled; accumulators are 5 statically-named arrays selected by a wave-uniform
// branch on j (runtime-indexed register arrays would go to scratch, rule #20).
__global__ __launch_bounds__(256) void k3_new(
    const float* __restrict__ c1, const float* __restrict__ PA,
    const float* __restrict__ gsw, const float* __restrict__ gsb,
    const float* __restrict__ gdg, const float* __restrict__ gdbt,
    const float* __restrict__ gsg, const float* __restrict__ gsbt,
    float2* st, float* __restrict__ newb)
{
  __shared__ float pa[5][25][28];
  __shared__ float gw[5][16][20];
  __shared__ float xdl[4][16][28];
  __shared__ float zz[4][25][20];
  __shared__ float cA[16], cB[16];
  __shared__ float c2A[5][16], c2B[5][16];
  __shared__ float bst[4][128];
  const int tid = threadIdx.x;
  const int n = blockIdx.y;
  const int wv = tid >> 6, lane = tid & 63, oc = lane & 15, vg = lane >> 4;
  const int t = blockIdx.x*4 + wv;
  float base[7], ac1[7], ac2[7], ac3[7], ac4[7];
  #pragma unroll
  for (int k = 0; k < 7; k++){ base[k]=0.f; ac1[k]=0.f; ac2[k]=0.f; ac3[k]=0.f; ac4[k]=0.f; }

  #pragma unroll 1
  for (int l = 0; l < 3; l++){
    __syncthreads();   // WAR: previous-l readers of pa/gw/coefs done
    for (int i = tid; i < 5*625; i += 256){ int j = i/625, r = i - j*625; pa[j][r/25][r%25] = PA[(l*5+j)*625 + r]; }
    for (int i = tid; i < 5*256; i += 256){ int j = i >> 8, r = i & 255; gw[j][r>>4][r&15] = gsw[(l*5+j)*256 + r]; }
    if (tid < 16){
      float2 ab = bncoef(st, l*16+tid, gdg[l*16+tid], gdbt[l*16+tid]);
      cA[tid] = ab.x; cB[tid] = ab.y;
    }
    if (tid < 80){
      int j = tid >> 4, o = tid & 15;
      float2 ab = bncoef(st, 48 + (l*5+j)*16 + o, gsg[(l*5+j)*16+o], gsbt[(l*5+j)*16+o]);
      c2A[j][o] = ab.x; c2B[j][o] = ab.y;
    }
    __syncthreads();   // RAW: pa/gw/coefs visible to all waves
    const float* c1p = c1 + (size_t)((l*N_+n)*II)*TV + t*25;
    for (int idx = lane; idx < 400; idx += 64){
      int c = idx/25, v = idx - c*25;
      float val = c1p[c*TV + v];
      xdl[wv][c][v] = fmaxf(cA[c]*val + cB[c], 0.f);
    }
    // per-wave tile: no barrier
    float xdr[25];
    {
      const float4* xr4 = (const float4*)&xdl[wv][oc][0];
      #pragma unroll
      for (int u4 = 0; u4 < 6; u4++){
        float4 x4 = xr4[u4];
        xdr[u4*4+0]=x4.x; xdr[u4*4+1]=x4.y; xdr[u4*4+2]=x4.z; xdr[u4*4+3]=x4.w;
      }
      xdr[24] = xdl[wv][oc][24];
    }
    #pragma unroll 1
    for (int j = 0; j < 5; j++){
      #pragma unroll
      for (int k = 0; k < 7; k++){
        int v = vg + 4*k;
        if (v < 25){
          const float4* p4 = (const float4*)&pa[j][v][0];
          float zv = 0.f;
          #pragma unroll
          for (int u4 = 0; u4 < 6; u4++){
            float4 pp = p4[u4];
            zv += xdr[u4*4+0]*pp.x + xdr[u4*4+1]*pp.y + xdr[u4*4+2]*pp.z + xdr[u4*4+3]*pp.w;
          }
          zv += xdr[24]*pa[j][v][24];
          zz[wv][v][oc] = zv;
        }
      }
      float gwr[16];
      {
        const float4* g4 = (const float4*)&gw[j][oc][0];
        #pragma unroll
        for (int c4 = 0; c4 < 4; c4++){
          float4 gg = g4[c4];
          gwr[c4*4+0]=gg.x; gwr[c4*4+1]=gg.y; gwr[c4*4+2]=gg.z; gwr[c4*4+3]=gg.w;
        }
      }
      const float bjo = gsb[(l*5+j)*16 + oc];
      const float a2 = c2A[j][oc], b2 = c2B[j][oc];
      float ybuf[7];
      #pragma unroll
      for (int k = 0; k < 7; k++){
        int v = vg + 4*k;
        ybuf[k] = 0.f;
        if (v < 25){
          const float4* z4 = (const float4*)&zz[wv][v][0];
          float cv = bjo;
          #pragma unroll
          for (int c4 = 0; c4 < 4; c4++){
            float4 zf = z4[c4];
            cv += gwr[c4*4+0]*zf.x + gwr[c4*4+1]*zf.y + gwr[c4*4+2]*zf.z + gwr[c4*4+3]*zf.w;
          }
          ybuf[k] = a2*cv + b2;
        }
      }
      // wave-uniform branch on j; all register indices static
      if (j == 0){
        #pragma unroll
        for (int k = 0; k < 7; k++) base[k] += ybuf[k];
      } else if (j == 1){
        #pragma unroll
        for (int k = 0; k < 7; k++) ac1[k] += ybuf[k];
      } else if (j == 2){
        #pragma unroll
        for (int k = 0; k < 7; k++) ac2[k] += ybuf[k];
      } else if (j == 3){
        #pragma unroll
        for (int k = 0; k < 7; k++) ac3[k] += ybuf[k];
      } else {
        #pragma unroll
        for (int k = 0; k < 7; k++) ac4[k] += ybuf[k];
      }
    }
  }
  // new[g] = ys[g+1] (summed over l) + base (= sum_l ys[0])
  float* np = newb + (size_t)n*64*TV + t*25;
  float s0=0.f,q0=0.f,s1=0.f,q1=0.f,s2=0.f,q2=0.f,s3=0.f,q3=0.f;
  #pragma unroll
  for (int k = 0; k < 7; k++){
    int v = vg + 4*k;
    if (v < 25){
      float v0 = ac1[k] + base[k];
      float v1 = ac2[k] + base[k];
      float v2 = ac3[k] + base[k];
      float v3 = ac4[k] + base[k];
      np[(0*16+oc)*TV + v] = v0;
      np[(1*16+oc)*TV + v] = v1;
      np[(2*16+oc)*TV + v] = v2;
      np[(3*16+oc)*TV + v] = v3;
      s0 += v0; q0 += v0*v0;
      s1 += v1; q1 += v1*v1;
      s2 += v2; q2 += v2*v2;
      s3 += v3; q3 += v3*v3;
    }
  }
  s0 += __shfl_xor(s0,16); s0 += __shfl_xor(s0,32);
  q0 += __shfl_xor(q0,16); q0 += __shfl_xor(q0,32);
  s1 += __shfl_xor(s1,16); s1 += __shfl_xor(s1,32);
  q1 += __shfl_xor(q1,16); q1 += __shfl_xor(q1,32);
  s2 += __shfl_xor(s2,16); s2 += __shfl_xor(s2,32);
  q2 += __shfl_xor(q2,16); q2 += __shfl_xor(q2,32);
  s3 += __shfl_xor(s3,16); s3 += __shfl_xor(s3,32);
  q3 += __shfl_xor(q3,16); q3 += __shfl_xor(q3,32);
  if (vg == 0){
    bst[wv][2*(0*16+oc)] = s0; bst[wv][2*(0*16+oc)+1] = q0;
    bst[wv][2*(1*16+oc)] = s1; bst[wv][2*(1*16+oc)+1] = q1;
    bst[wv][2*(2*16+oc)] = s2; bst[wv][2*(2*16+oc)+1] = q2;
    bst[wv][2*(3*16+oc)] = s3; bst[wv][2*(3*16+oc)+1] = q3;
  }
  __syncthreads();
  float* stf = (float*)st;
  for (int i = tid; i < 128; i += 256)
    unsafeAtomicAdd(stf + 576 + i, bst[0][i]+bst[1][i]+bst[2][i]+bst[3][i]);
}

// ---------------- K4: xg = relu(bn(new)+x); y[k] = brw[k]*xg + brb[k]; stats(y) ----------------
__global__ __launch_bounds__(256) void k4_xg_branches(
    const float* __restrict__ x, const float* __restrict__ newb,
    const float* __restrict__ gbng, const float* __restrict__ gbnb,
    const float* __restrict__ brw, const float* __restrict__ brb,
    float2* st, float* __restrict__ xg, float* __restrict__ y)
{
  __shared__ float w[64*64];     // w[c*64+ko] = brw[ko*64+c]
  __shared__ float cA[64], cB[64], bias[64];
  __shared__ float bst[4][128];
  const int tid = threadIdx.x;
  for (int i = tid; i < 4096; i += 256){ int c = i >> 6, ko = i & 63; w[i] = brw[ko*64 + c]; }
  if (tid < 64){
    float2 ab = bncoef(st, 288+tid, gbng[tid], gbnb[tid]);
    cA[tid] = ab.x; cB[tid] = ab.y; bias[tid] = brb[tid];
  }
  __syncthreads();
  const int n = blockIdx.y;
  const int rem = blockIdx.x*256 + tid;
  const bool act = rem < TV;
  const float* xp  = x    + (size_t)n*64*TV + rem;
  const float* npx = newb + (size_t)n*64*TV + rem;
  float*       xgp = xg   + (size_t)n*64*TV + rem;
  float xgv[64];
  #pragma unroll
  for (int c = 0; c < 64; c++){
    float v = 0.f;
    if (act){
      v = fmaxf(cA[c]*npx[c*TV] + cB[c] + xp[c*TV], 0.f);
      xgp[c*TV] = v;
    }
    xgv[c] = v;
  }
  const int wv = tid >> 6, lane = tid & 63;
  #pragma unroll
  for (int k = 0; k < 4; k++){
    float acc[16];
    #pragma unroll
    for (int o = 0; o < 16; o++) acc[o] = act ? bias[k*16+o] : 0.f;
    #pragma unroll
    for (int c = 0; c < 64; c++){
      float xv = xgv[c];
      const float4* w4 = (const float4*)&w[c*64 + k*16];
      #pragma unroll
      for (int o4 = 0; o4 < 4; o4++){
        float4 ww = w4[o4];
        acc[o4*4+0] += ww.x*xv; acc[o4*4+1] += ww.y*xv;
        acc[o4*4+2] += ww.z*xv; acc[o4*4+3] += ww.w*xv;
      }
    }
    if (act){
      float* yp = y + (size_t)((k*N_+n)*16)*TV + rem;
      #pragma unroll
      for (int o = 0; o < 16; o++) yp[o*TV] = acc[o];
    }
    #pragma unroll
    for (int o = 0; o < 16; o++){
      float s = acc[o], q = acc[o]*acc[o];
      #pragma unroll
      for (int m = 32; m; m >>= 1){ s += __shfl_xor(s, m); q += __shfl_xor(q, m); }
      if (lane == 0){ bst[wv][2*(k*16+o)] = s; bst[wv][2*(k*16+o)+1] = q; }
    }
  }
  __syncthreads();
  float* stf = (float*)st;
  for (int i = tid; i < 128; i += 256)
    unsafeAtomicAdd(stf + 704 + i, bst[0][i]+bst[1][i]+bst[2][i]+bst[3][i]);
}

// ---------------- K5: temporal convs (d=1,2) + maxpool branch, pre-final-BN values + stats -----
__global__ __launch_bounds__(256) void k5_temporal(
    const float* __restrict__ y, const float* __restrict__ tcw, const float* __restrict__ tcbias,
    const float* __restrict__ brg, const float* __restrict__ brbt,
    float2* st, float* __restrict__ tp)
{
  __shared__ float wt[2*16*5*16];   // [k][c][ks][o]
  __shared__ float cAy[48], cBy[48];
  __shared__ float bst[4][96];
  const int tid = threadIdx.x;
  for (int i = tid; i < 2560; i += 256){
    int k = i/1280, r = i - k*1280, c = r/80, r2 = r - c*80, ks = r2 >> 4, o = r2 & 15;
    wt[i] = tcw[((k*16+o)*16 + c)*5 + ks];
  }
  if (tid < 48){
    float2 ab = bncoef(st, 352+tid, brg[tid], brbt[tid]);
    cAy[tid] = ab.x; cBy[tid] = ab.y;
  }
  __syncthreads();
  const int n = blockIdx.y;
  const int rem = blockIdx.x*256 + tid;
  const bool act = rem < TV;
  const int t = rem/25, v = rem - t*25;
  const int wv = tid >> 6, lane = tid & 63;
  #pragma unroll
  for (int k = 0; k < 2; k++){
    const int d = k + 1;
    float acc[16];
    #pragma unroll
    for (int o = 0; o < 16; o++) acc[o] = act ? tcbias[k*16+o] : 0.f;
    if (act){
      const float* yp = y + (size_t)((k*N_+n)*16)*TV;
      #pragma unroll
      for (int ks = 0; ks < 5; ks++){
        int ttt = t + d*(ks-2);
        if (ttt >= 0 && ttt < T_){
          int off = ttt*25 + v;
          #pragma unroll
          for (int c = 0; c < 16; c++){
            float val = fmaxf(cAy[k*16+c]*yp[c*TV + off] + cBy[k*16+c], 0.f);
            const float4* w4 = (const float4*)&wt[((k*16+c)*5 + ks)*16];
            #pragma unroll
            for (int o4 = 0; o4 < 4; o4++){
              float4 ww = w4[o4];
              acc[o4*4+0] += ww.x*val; acc[o4*4+1] += ww.y*val;
              acc[o4*4+2] += ww.z*val; acc[o4*4+3] += ww.w*val;
            }
          }
        }
      }
      float* op = tp + (size_t)k*6553600 + (size_t)(n*16)*TV + rem;
      #pragma unroll
      for (int o = 0; o < 16; o++) op[o*TV] = acc[o];
    }
    #pragma unroll
    for (int o = 0; o < 16; o++){
      float s = acc[o], q = acc[o]*acc[o];
      #pragma unroll
      for (int m = 32; m; m >>= 1){ s += __shfl_xor(s, m); q += __shfl_xor(q, m); }
      if (lane == 0){ bst[wv][2*(k*16+o)] = s; bst[wv][2*(k*16+o)+1] = q; }
    }
  }
  { // maxpool branch (k=2)
    float mx[16];
    #pragma unroll
    for (int o = 0; o < 16; o++) mx[o] = -1e30f;
    if (act){
      const float* yp = y + (size_t)((2*N_+n)*16)*TV;
      #pragma unroll
      for (int dt = -1; dt <= 1; dt++){
        int ttt = t + dt;
        if (ttt >= 0 && ttt < T_){
          int off = ttt*25 + v;
          #pragma unroll
          for (int o = 0; o < 16; o++){
            float val = fmaxf(cAy[32+o]*yp[o*TV + off] + cBy[32+o], 0.f);
            mx[o] = fmaxf(mx[o], val);
          }
        }
      }
      float* op = tp + (size_t)2*6553600 + (size_t)(n*16)*TV + rem;
      #pragma unroll
      for (int o = 0; o < 16; o++) op[o*TV] = mx[o];
    } else {
      #pragma unroll
      for (int o = 0; o < 16; o++) mx[o] = 0.f;
    }
    #pragma unroll
    for (int o = 0; o < 16; o++){
      float s = mx[o], q = mx[o]*mx[o];
      #pragma unroll
      for (int m = 32; m; m >>= 1){ s += __shfl_xor(s, m); q += __shfl_xor(q, m); }
      if (lane == 0){ bst[wv][64 + 2*o] = s; bst[wv][64 + 2*o + 1] = q; }
    }
  }
  __syncthreads();
  float* stf = (float*)st;
  for (int i = tid; i < 96; i += 256)
    unsafeAtomicAdd(stf + 832 + i, bst[0][i]+bst[1][i]+bst[2][i]+bst[3][i]);
}

// ---------------- K6: final BNs + concat + residual + relu ----------------
__global__ __launch_bounds__(256) void k6_final(
    const float* __restrict__ tp, const float* __restrict__ y, const float* __restrict__ xg,
    const float* __restrict__ tcg, const float* __restrict__ tcbt,
    const float* __restrict__ mpg, const float* __restrict__ mpb,
    const float* __restrict__ brg, const float* __restrict__ brbt,
    const float2* __restrict__ st, float* __restrict__ out)
{
  __shared__ float cA[64], cB[64];
  const int tid = threadIdx.x;
  if (tid < 64){
    int o = tid & 15;
    float2 ab;
    if (tid < 32)      ab = bncoef(st, 416 + tid, tcg[tid], tcbt[tid]);
    else if (tid < 48) ab = bncoef(st, 448 + o, mpg[o], mpb[o]);
    else               ab = bncoef(st, 400 + o, brg[48+o], brbt[48+o]);
    cA[tid] = ab.x; cB[tid] = ab.y;
  }
  __syncthreads();
  const int n = blockIdx.y;
  const int rem = blockIdx.x*256 + tid;
  if (rem >= TV) return;
  const float* xgp = xg + (size_t)n*64*TV + rem;
  float* op = out + (size_t)n*64*TV + rem;
  #pragma unroll
  for (int ch = 0; ch < 64; ch++){
    int o = ch & 15;
    float sv;
    if (ch < 48) sv = tp[(size_t)(ch>>4)*6553600 + (size_t)(n*16+o)*TV + rem];
    else         sv = y[(size_t)((3*N_+n)*16 + o)*TV + rem];
    float val = cA[ch]*sv + cB[ch] + xgp[ch*TV];
    op[ch*TV] = fmaxf(val, 0.f);
  }
}

extern "C" void kernel_launch(void* const* d_in, const int* in_sizes, int n_in,
                              void* d_out, int out_size, void* d_ws, size_t ws_size,
                              hipStream_t stream) {
  (void)in_sizes; (void)n_in; (void)out_size; (void)ws_size;
  const float* x    = (const float*)d_in[0];
  const float* PA   = (const float*)d_in[1];
  const float* gdw  = (const float*)d_in[2];
  const float* gdb  = (const float*)d_in[3];
  const float* gdg  = (const float*)d_in[4];
  const float* gdbt = (const float*)d_in[5];
  const float* gsw  = (const float*)d_in[6];
  const float* gsb  = (const float*)d_in[7];
  const float* gsg  = (const float*)d_in[8];
  const float* gsbt = (const float*)d_in[9];
  const float* gbng = (const float*)d_in[10];
  const float* gbnb = (const float*)d_in[11];
  const float* brw  = (const float*)d_in[12];
  const float* brb  = (const float*)d_in[13];
  const float* brg  = (const float*)d_in[14];
  const float* brbt = (const float*)d_in[15];
  const float* tcw  = (const float*)d_in[16];
  const float* tcbias=(const float*)d_in[17];
  const float* tcg  = (const float*)d_in[18];
  const float* tcbt = (const float*)d_in[19];
  const float* mpg  = (const float*)d_in[20];
  const float* mpb  = (const float*)d_in[21];

  char* ws = (char*)d_ws;
  float2* st  = (float2*)ws;                                   // 4 KB stats
  float* c1   = (float*)(ws + 4096);                           // 78.6 MB (reused as tp later)
  float* tp   = c1;
  float* newb = (float*)(ws + 4096 + 78643200);                // 104.9 MB
  float* xg   = (float*)(ws + 4096 + 78643200 + 104857600);    // 104.9 MB
  float* y    = (float*)(ws + 4096 + 78643200 + 209715200);    // 104.9 MB

  hipMemsetAsync(st, 0, 4096, stream);
  dim3 b(256);
  k1_conv_dw     <<<dim3(13,128),   b, 0, stream>>>(x, gdw, gdb, c1, st);
  k2_spatial_stats<<<dim3(32,128,3), b, 0, stream>>>(c1, PA, gsw, gsb, gdg, gdbt, st);
  k3_new         <<<dim3(32,128),   b, 0, stream>>>(c1, PA, gsw, gsb, gdg, gdbt, gsg, gsbt, st, newb);
  k4_xg_branches <<<dim3(13,128),   b, 0, stream>>>(x, newb, gbng, gbnb, brw, brb, st, xg, y);
  k5_temporal    <<<dim3(13,128),   b, 0, stream>>>(y, tcw, tcbias, brg, brbt, st, tp);
  k6_final       <<<dim3(13,128),   b, 0, stream>>>(tp, y, xg, tcg, tcbt, mpg, mpb, brg, brbt, st, (float*)d_out);
}